// Round 1
// baseline (1655.029 us; speedup 1.0000x reference)
//
#include <hip/hip_runtime.h>
#include <hip/hip_bf16.h>

// Attention: B=2,H=16,S=2048,D=64; outputs (out[B,H,S,D], p_attn[B,H,S,S]) fp32.
#define BH_N   32
#define S_LEN  2048
#define D_DIM  64
#define SCALE_F 0.125f

typedef short bf16x8 __attribute__((ext_vector_type(8)));
typedef float f32x4  __attribute__((ext_vector_type(4)));

__device__ __forceinline__ short f2bf(float x) {
    union { __hip_bfloat16 h; short s; } u;
    u.h = __float2bfloat16(x);   // RNE
    return u.s;
}

// Kernel A: e = exp(((Q K^T) + adjust) * scale), masked -> 0, written unnormalized
// into the p_attn region; per-row sums of e atomically accumulated into lsum.
// Grid: (ktile=S/64, qtile=S/64, bh). Block: 256 (4 waves); wave w owns 16 q-rows.
__global__ __launch_bounds__(256) void score_kernel(
    const float* __restrict__ Q, const float* __restrict__ Km,
    const int* __restrict__ mask, const float* __restrict__ adj,
    float* __restrict__ p, float* __restrict__ lsum, int l_stride)
{
    const int ktile = blockIdx.x;
    const int qtile = blockIdx.y;
    const int bh    = blockIdx.z;
    const int b     = bh >> 4;          // H = 16
    const int wave  = threadIdx.x >> 6;
    const int lane  = threadIdx.x & 63;
    const int l16   = lane & 15;
    const int quad  = lane >> 4;

    const int qbase = qtile * 64 + wave * 16;

    // A fragments: A[m=l16][k=quad*8+j], two 32-wide D halves
    const float* qrow = Q + ((size_t)bh * S_LEN + qbase + l16) * D_DIM;
    bf16x8 afrag[2];
    #pragma unroll
    for (int kh = 0; kh < 2; ++kh) {
        const float4 v0 = *(const float4*)(qrow + kh * 32 + quad * 8);
        const float4 v1 = *(const float4*)(qrow + kh * 32 + quad * 8 + 4);
        afrag[kh][0] = f2bf(v0.x); afrag[kh][1] = f2bf(v0.y);
        afrag[kh][2] = f2bf(v0.z); afrag[kh][3] = f2bf(v0.w);
        afrag[kh][4] = f2bf(v1.x); afrag[kh][5] = f2bf(v1.y);
        afrag[kh][6] = f2bf(v1.z); afrag[kh][7] = f2bf(v1.w);
    }

    float rowsum[4] = {0.f, 0.f, 0.f, 0.f};

    #pragma unroll
    for (int nt = 0; nt < 4; ++nt) {
        const int kb = ktile * 64 + nt * 16;
        // B fragments from K rows (B^T-style): B[n=l16][k=quad*8+j]
        const float* krow = Km + ((size_t)bh * S_LEN + kb + l16) * D_DIM;
        f32x4 acc = {0.f, 0.f, 0.f, 0.f};
        #pragma unroll
        for (int kh = 0; kh < 2; ++kh) {
            const float4 v0 = *(const float4*)(krow + kh * 32 + quad * 8);
            const float4 v1 = *(const float4*)(krow + kh * 32 + quad * 8 + 4);
            bf16x8 bfrag;
            bfrag[0] = f2bf(v0.x); bfrag[1] = f2bf(v0.y);
            bfrag[2] = f2bf(v0.z); bfrag[3] = f2bf(v0.w);
            bfrag[4] = f2bf(v1.x); bfrag[5] = f2bf(v1.y);
            bfrag[6] = f2bf(v1.z); bfrag[7] = f2bf(v1.w);
            acc = __builtin_amdgcn_mfma_f32_16x16x32_bf16(afrag[kh], bfrag, acc, 0, 0, 0);
        }
        // C/D layout: col = l16, row = quad*4 + r
        #pragma unroll
        for (int r = 0; r < 4; ++r) {
            const int q = qbase + quad * 4 + r;
            const int k = kb + l16;
            const size_t sidx = ((size_t)bh * S_LEN + q) * S_LEN + k;
            const size_t midx = ((size_t)b  * S_LEN + q) * S_LEN + k;   // mask broadcast over H
            const float s = (acc[r] + adj[sidx]) * SCALE_F;
            const float e = mask[midx] ? 0.f : __expf(s);
            p[sidx] = e;
            rowsum[r] += e;
        }
    }

    // reduce each row's partial sum over the 16 lanes of a quad, one atomic per row
    #pragma unroll
    for (int r = 0; r < 4; ++r) {
        float v = rowsum[r];
        v += __shfl_xor(v, 1);
        v += __shfl_xor(v, 2);
        v += __shfl_xor(v, 4);
        v += __shfl_xor(v, 8);
        if (l16 == 0) {
            const int q = qbase + quad * 4 + r;
            atomicAdd(lsum + (size_t)(bh * S_LEN + q) * l_stride, v);
        }
    }
}

// Kernel B: p = e / l written in place (final p_attn), out = P @ V via bf16 MFMA.
// Grid: (qtile=S/64, bh). Block: 256 (4 waves); wave w owns 16 q-rows, all of K.
__global__ __launch_bounds__(256) void pv_kernel(
    const float* __restrict__ V, float* __restrict__ p,
    const float* __restrict__ lsum, int l_stride,
    float* __restrict__ out)
{
    const int qtile = blockIdx.x;
    const int bh    = blockIdx.y;
    const int wave  = threadIdx.x >> 6;
    const int lane  = threadIdx.x & 63;
    const int l16   = lane & 15;
    const int quad  = lane >> 4;
    const int qbase = qtile * 64 + wave * 16;

    const float inv_l = 1.0f / lsum[(size_t)(bh * S_LEN + qbase + l16) * l_stride];

    f32x4 acc[4];
    #pragma unroll
    for (int nt = 0; nt < 4; ++nt) acc[nt] = (f32x4){0.f, 0.f, 0.f, 0.f};

    float* prow = p + ((size_t)bh * S_LEN + qbase + l16) * S_LEN;
    const float* vbase = V + (size_t)bh * S_LEN * D_DIM;

    for (int ks = 0; ks < S_LEN / 32; ++ks) {
        // A-frag: P[m=l16][k=quad*8+j]; scale in place -> final p_attn
        float* src = prow + ks * 32 + quad * 8;
        const float4 v0 = *(const float4*)src;
        const float4 v1 = *(const float4*)(src + 4);
        float pa[8] = { v0.x * inv_l, v0.y * inv_l, v0.z * inv_l, v0.w * inv_l,
                        v1.x * inv_l, v1.y * inv_l, v1.z * inv_l, v1.w * inv_l };
        *(float4*)src       = make_float4(pa[0], pa[1], pa[2], pa[3]);
        *(float4*)(src + 4) = make_float4(pa[4], pa[5], pa[6], pa[7]);
        bf16x8 a;
        #pragma unroll
        for (int j = 0; j < 8; ++j) a[j] = f2bf(pa[j]);

        const float* vrow = vbase + (size_t)(ks * 32 + quad * 8) * D_DIM;
        #pragma unroll
        for (int nt = 0; nt < 4; ++nt) {
            // B-frag: V[k=quad*8+j][n=nt*16+l16]
            bf16x8 bv;
            #pragma unroll
            for (int j = 0; j < 8; ++j)
                bv[j] = f2bf(vrow[(size_t)j * D_DIM + nt * 16 + l16]);
            acc[nt] = __builtin_amdgcn_mfma_f32_16x16x32_bf16(a, bv, acc[nt], 0, 0, 0);
        }
    }

    #pragma unroll
    for (int nt = 0; nt < 4; ++nt) {
        #pragma unroll
        for (int r = 0; r < 4; ++r) {
            out[((size_t)bh * S_LEN + qbase + quad * 4 + r) * D_DIM + nt * 16 + l16] =
                acc[nt][r];
        }
    }
}

extern "C" void kernel_launch(void* const* d_in, const int* in_sizes, int n_in,
                              void* d_out, int out_size, void* d_ws, size_t ws_size,
                              hipStream_t stream) {
    const float* Q    = (const float*)d_in[0];
    const float* Km   = (const float*)d_in[1];
    const float* V    = (const float*)d_in[2];
    const int*   mask = (const int*)d_in[3];   // bool -> int32 assumption (risk noted)
    const float* adj  = (const float*)d_in[4];

    float* out = (float*)d_out;                              // [B,H,S,D]
    float* p   = out + (size_t)BH_N * S_LEN * D_DIM;         // [B,H,S,S]

    // Row-sum accumulator: prefer d_ws; fall back to stashing in out[bh][q][0]
    // (safe: each pv_kernel wave reads its own rows' l before writing its out rows).
    float* l_ptr;
    int    l_stride;
    const size_t lbytes = (size_t)BH_N * S_LEN * sizeof(float);
    if (ws_size >= lbytes) {
        l_ptr = (float*)d_ws; l_stride = 1;
        hipMemsetAsync(d_ws, 0, lbytes, stream);
    } else {
        l_ptr = out; l_stride = D_DIM;
        hipMemsetAsync(out, 0, (size_t)BH_N * S_LEN * D_DIM * sizeof(float), stream);
    }

    score_kernel<<<dim3(S_LEN / 64, S_LEN / 64, BH_N), 256, 0, stream>>>(
        Q, Km, mask, adj, p, l_ptr, l_stride);
    pv_kernel<<<dim3(S_LEN / 64, BH_N), 256, 0, stream>>>(
        V, p, l_ptr, l_stride, out);
}